// Round 8
// baseline (398.176 us; speedup 1.0000x reference)
//
#include <hip/hip_runtime.h>
#include <math.h>

// Problem constants
#define Tn 30
#define Bn 16384
#define Hn 100
#define Pn 7

// Tiling: gates padded 100->128 units => N=512 (32 n-tiles); K padded 100->128 (4 kt of 32).
// 256 blocks x 1024 threads (16 waves), __launch_bounds__(1024,4) -> VGPR cap 128 (NO spills;
// R7's plain (1024) defaulted to a 64-VGPR cap and spilled 250 GB of scratch).
// Wave (ag = w&7, rh = w>>3) owns unit-block ag (16 units, all 4 gates) for row-groups
// {2rh, 2rh+1}. B-frags (16/wave = 64 VGPR) in registers. gin2 in 16 packed-bf16 VGPRs
// (wave-private cells -- LDS round-trip removed). h double-buffered in LDS, frag-major
// [rg][kt][lane][8] -> lane-contiguous conflict-free ds_read_b128. 1 barrier/step.
#define NFRAG 128                      // B-frags per matrix (32 nt x 4 kt)
#define FRAG_BYTES (NFRAG * 64 * 16)   // 131072 per matrix
#define WS_FRAG_OFF 4096
#define WS_W2_OFF (WS_FRAG_OFF + 3 * FRAG_BYTES)   // 28 W2 frags (7 ps x 4 kt)
#define HBF_USH 8192                   // one h buffer: 4 rg x 4 kt x 64 lanes x 8 ush (16 KB)

typedef __attribute__((ext_vector_type(8))) short short8;   // 8 bf16 (4 VGPRs)
typedef __attribute__((ext_vector_type(4))) float floatx4;  // MFMA C/D

__device__ __forceinline__ float rcp_(float v) { return __builtin_amdgcn_rcpf(v); }
__device__ __forceinline__ float sig_(float v) { return rcp_(1.0f + __expf(-v)); }
__device__ __forceinline__ float tanh_(float v) { return 1.0f - 2.0f * rcp_(__expf(2.0f * v) + 1.0f); }
__device__ __forceinline__ unsigned f2bf(float v) {
    unsigned u = __float_as_uint(v);
    return (u + 0x7FFFu + ((u >> 16) & 1u)) >> 16;   // RNE
}

// A-frag read: buf[rg][kt][lane][8] -- 64 lanes x 16B contiguous (conflict-free b128)
__device__ __forceinline__ short8 ld_af(const unsigned short* buf, int rg, int kt, int lane) {
    return *(const short8*)(buf + ((rg * 4 + kt) * 64 + lane) * 8);
}

// Merged prep: gid<512 -> u1/wc1 rank-1 FC1 fold; else pack Whh1/Wih2/Whh2 + W2 B-frags.
// B[k][n]: n = lane&15, k = (lane>>4)*8 + jj  (16x16x32 bf16 B mapping, HW-verified R4-R7).
__global__ void prep_kernel(const float* __restrict__ W1, const float* __restrict__ b1,
                            const float* __restrict__ Wih1, const float* __restrict__ bih1,
                            const float* __restrict__ bhh1, const float* __restrict__ Whh1,
                            const float* __restrict__ Wih2, const float* __restrict__ Whh2,
                            const float* __restrict__ W2, float* __restrict__ ws) {
    int gid = blockIdx.x * 256 + threadIdx.x;   // 512 + 3*8192 + 1792 = 26880 total
    if (gid < 512) {
        int j = gid;
        if (j < 400) {
            float u = 0.f, w = 0.f;
            for (int k = 0; k < Hn; ++k) {
                float a = Wih1[j * Hn + k];
                u += a * W1[k];
                w += a * b1[k];
            }
            ws[j] = u;
            ws[400 + j] = w + bih1[j] + bhh1[j];
        }
        return;
    }
    int g = gid - 512;
    int lane = g & 63;
    int l = lane & 15, q = lane >> 4;
    unsigned short hh[8];
    uint4 u;
    if (g < 3 * NFRAG * 64) {
        int mat = g / (NFRAG * 64);
        int f = (g % (NFRAG * 64)) >> 6;
        int nt = f >> 2, kt = f & 3;
        int G = nt >> 3, ag = nt & 7;
        int j = ag * 16 + l;
        const float* W = (mat == 0) ? Whh1 : (mat == 1) ? Wih2 : Whh2;
        const float* wrow = W + (G * Hn + (j < Hn ? j : 0)) * Hn;
        int kbase = kt * 32 + q * 8;
#pragma unroll
        for (int jj = 0; jj < 8; ++jj) {
            int k = kbase + jj;
            hh[jj] = (j < Hn && k < Hn) ? (unsigned short)f2bf(wrow[k]) : (unsigned short)0;
        }
        u.x = (unsigned)hh[0] | ((unsigned)hh[1] << 16);
        u.y = (unsigned)hh[2] | ((unsigned)hh[3] << 16);
        u.z = (unsigned)hh[4] | ((unsigned)hh[5] << 16);
        u.w = (unsigned)hh[6] | ((unsigned)hh[7] << 16);
        ((uint4*)((char*)ws + WS_FRAG_OFF + mat * FRAG_BYTES))[f * 64 + lane] = u;
    } else {
        int t = g - 3 * NFRAG * 64;             // 0..1791
        int f = t >> 6;                         // ps*4 + kt
        int ps = f >> 2, kt = f & 3;
        int kbase = kt * 32 + q * 8;
#pragma unroll
        for (int jj = 0; jj < 8; ++jj) {
            int k = kbase + jj;
            hh[jj] = (l < Pn && k < Hn) ? (unsigned short)f2bf(W2[l * (Pn * Hn) + ps * Hn + k])
                                        : (unsigned short)0;
        }
        u.x = (unsigned)hh[0] | ((unsigned)hh[1] << 16);
        u.y = (unsigned)hh[2] | ((unsigned)hh[3] << 16);
        u.z = (unsigned)hh[4] | ((unsigned)hh[5] << 16);
        u.w = (unsigned)hh[6] | ((unsigned)hh[7] << 16);
        ((uint4*)((char*)ws + WS_W2_OFF))[f * 64 + lane] = u;
    }
}

__global__ __launch_bounds__(1024, 4) void lstm_fused(
    const float* __restrict__ x,     // (T,B)
    const float* __restrict__ ws,    // u1/wc1 + packed frags
    const float* __restrict__ bih2,
    const float* __restrict__ bhh2,
    const float* __restrict__ b2,    // (7,)
    float* __restrict__ out)         // (B,7)
{
    __shared__ unsigned short sm[2 * HBF_USH];  // 32 KB: h double buffer, frag-major
    unsigned short* hb0 = sm;
    unsigned short* hb1 = sm + HBF_USH;

    const int tid = threadIdx.x;
    const int wave = tid >> 6, lane = tid & 63;
    const int l = lane & 15, q = lane >> 4;
    const int ag = wave & 7, rh = wave >> 3;
    const int jcol = ag * 16 + l;               // unit column (0..127; <100 real)
    const int rowbase = blockIdx.x * 64;

    // h-write offset for this lane's unit jcol (A-layout target):
    // ush addr = rg*2048 + (4q+r)*8 + hwoff ; one b16 per lane (2-way same-dword = free)
    const int qa = ((ag & 1) << 1) | (l >> 3);
    const int hwoff = (ag >> 1) * 512 + qa * 128 + (l & 7);

    // zero both h buffers (covers K-pad; pad units compute h=0 exactly each step)
    for (int i = tid; i < HBF_USH; i += 1024) ((unsigned*)sm)[i] = 0;

    // this wave's 16 Whh1 B-frags -> registers (64 VGPR, held for all 30 steps)
    short8 bf[4][4];   // [G][kt]
    const short8* fr0 = (const short8*)((const char*)ws + WS_FRAG_OFF);
#pragma unroll
    for (int G = 0; G < 4; ++G)
#pragma unroll
        for (int kt = 0; kt < 4; ++kt)
            bf[G][kt] = fr0[((((G << 3) | ag) << 2) + kt) * 64 + lane];

    float u1v[4], wc1v[4];
#pragma unroll
    for (int G = 0; G < 4; ++G) {
        u1v[G] = (jcol < Hn) ? ws[G * Hn + jcol] : 0.f;
        wc1v[G] = (jcol < Hn) ? ws[400 + G * Hn + jcol] : 0.f;
    }
    floatx4 cst[2];   // cell state per rg2, rows 4q+r, unit jcol
    cst[0] = (floatx4){0.f, 0.f, 0.f, 0.f};
    cst[1] = (floatx4){0.f, 0.f, 0.f, 0.f};

    __syncthreads();   // h buffers zeroed

    // ---- Phase 1: LSTM1, 30 steps, 1 barrier/step ----
    for (int t = 0; t < Tn; ++t) {
        const unsigned short* hc = (t & 1) ? hb1 : hb0;
        unsigned short* hn = (t & 1) ? hb0 : hb1;
#pragma unroll
        for (int rg2 = 0; rg2 < 2; ++rg2) {
            const int rg = 2 * rh + rg2;
            float4 xv = *(const float4*)(x + t * Bn + rowbase + rg * 16 + 4 * q);
            floatx4 acc[4];
#pragma unroll
            for (int G = 0; G < 4; ++G)
#pragma unroll
                for (int r = 0; r < 4; ++r)
                    acc[G][r] = fmaf(xv[r], u1v[G], wc1v[G]);
#pragma unroll
            for (int kt = 0; kt < 4; ++kt) {
                short8 a = ld_af(hc, rg, kt, lane);
#pragma unroll
                for (int G = 0; G < 4; ++G)
                    acc[G] = __builtin_amdgcn_mfma_f32_16x16x32_bf16(a, bf[G][kt], acc[G], 0, 0, 0);
            }
#pragma unroll
            for (int r = 0; r < 4; ++r) {
                float iv = sig_(acc[0][r]);
                float fv = sig_(acc[1][r]);
                float gv = tanh_(acc[2][r]);
                float ov = sig_(acc[3][r]);
                float cc = fv * cst[rg2][r] + iv * gv;
                cst[rg2][r] = cc;
                hn[rg * 2048 + (4 * q + r) * 8 + hwoff] = (unsigned short)f2bf(ov * tanh_(cc));
            }
        }
        __syncthreads();
    }
    // hb0 holds `last` (h after t=29).

    // ---- Wih2 frags; gin2 = bias2 + last·Wih2^T kept in 16 packed-bf16 VGPRs ----
    {
        const short8* fr = (const short8*)((const char*)ws + WS_FRAG_OFF + FRAG_BYTES);
#pragma unroll
        for (int G = 0; G < 4; ++G)
#pragma unroll
            for (int kt = 0; kt < 4; ++kt)
                bf[G][kt] = fr[((((G << 3) | ag) << 2) + kt) * 64 + lane];
    }
    uint2 g2r[2][4];   // [rg2][G] packed bf16 gin2 (wave-private cells)
    {
        float bv[4];
#pragma unroll
        for (int G = 0; G < 4; ++G)
            bv[G] = (jcol < Hn) ? (bih2[G * Hn + jcol] + bhh2[G * Hn + jcol]) : 0.f;
#pragma unroll
        for (int rg2 = 0; rg2 < 2; ++rg2) {
            const int rg = 2 * rh + rg2;
            floatx4 acc[4];
#pragma unroll
            for (int G = 0; G < 4; ++G)
                acc[G] = (floatx4){bv[G], bv[G], bv[G], bv[G]};
#pragma unroll
            for (int kt = 0; kt < 4; ++kt) {
                short8 a = ld_af(hb0, rg, kt, lane);
#pragma unroll
                for (int G = 0; G < 4; ++G)
                    acc[G] = __builtin_amdgcn_mfma_f32_16x16x32_bf16(a, bf[G][kt], acc[G], 0, 0, 0);
            }
#pragma unroll
            for (int G = 0; G < 4; ++G) {
                g2r[rg2][G].x = f2bf(acc[G][0]) | (f2bf(acc[G][1]) << 16);
                g2r[rg2][G].y = f2bf(acc[G][2]) | (f2bf(acc[G][3]) << 16);
            }
        }
    }
    // ---- Whh2 frags ----
    {
        const short8* fr = (const short8*)((const char*)ws + WS_FRAG_OFF + 2 * FRAG_BYTES);
#pragma unroll
        for (int G = 0; G < 4; ++G)
#pragma unroll
            for (int kt = 0; kt < 4; ++kt)
                bf[G][kt] = fr[((((G << 3) | ag) << 2) + kt) * 64 + lane];
    }

    // ---- Phase 2: LSTM2, 7 steps; FC2 via MFMA on waves ag<2 (myrg = 2rh+ag) ----
    const short8* w2fr = (const short8*)((const char*)ws + WS_W2_OFF);
    floatx4 yfc = (floatx4){0.f, 0.f, 0.f, 0.f};
    const int myrg = 2 * rh + ag;

    for (int ps = 0; ps < Pn; ++ps) {
        int t = Tn + ps;
        const unsigned short* hc = (t & 1) ? hb1 : hb0;
        unsigned short* hn = (t & 1) ? hb0 : hb1;
#pragma unroll
        for (int rg2 = 0; rg2 < 2; ++rg2) {
            const int rg = 2 * rh + rg2;
            floatx4 acc[4];
#pragma unroll
            for (int G = 0; G < 4; ++G) {
                acc[G][0] = __uint_as_float(g2r[rg2][G].x << 16);
                acc[G][1] = __uint_as_float(g2r[rg2][G].x & 0xFFFF0000u);
                acc[G][2] = __uint_as_float(g2r[rg2][G].y << 16);
                acc[G][3] = __uint_as_float(g2r[rg2][G].y & 0xFFFF0000u);
            }
#pragma unroll
            for (int kt = 0; kt < 4; ++kt) {
                short8 a = ld_af(hc, rg, kt, lane);
#pragma unroll
                for (int G = 0; G < 4; ++G)
                    acc[G] = __builtin_amdgcn_mfma_f32_16x16x32_bf16(a, bf[G][kt], acc[G], 0, 0, 0);
            }
#pragma unroll
            for (int r = 0; r < 4; ++r) {
                float iv = sig_(acc[0][r]);
                float fv = sig_(acc[1][r]);
                float gv = tanh_(acc[2][r]);
                float ov = sig_(acc[3][r]);
                float cc = fv * cst[rg2][r] + iv * gv;
                cst[rg2][r] = cc;
                hn[rg * 2048 + (4 * q + r) * 8 + hwoff] = (unsigned short)f2bf(ov * tanh_(cc));
            }
        }
        // FC2: y[row][p] += h2^(ps) · W2-slice(ps-1); hc holds h2 of previous step (stable)
        if (ag < 2 && ps >= 1) {
#pragma unroll
            for (int kt = 0; kt < 4; ++kt) {
                short8 a = ld_af(hc, myrg, kt, lane);
                short8 wf = w2fr[((ps - 1) * 4 + kt) * 64 + lane];
                yfc = __builtin_amdgcn_mfma_f32_16x16x32_bf16(a, wf, yfc, 0, 0, 0);
            }
        }
        __syncthreads();
    }

    // ---- final FC2 (h2^(7) in hb1, slice 6), bias + sigmoid, store ----
    if (ag < 2) {
#pragma unroll
        for (int kt = 0; kt < 4; ++kt) {
            short8 a = ld_af(hb1, myrg, kt, lane);
            short8 wf = w2fr[(6 * 4 + kt) * 64 + lane];
            yfc = __builtin_amdgcn_mfma_f32_16x16x32_bf16(a, wf, yfc, 0, 0, 0);
        }
        if (l < Pn) {
            float bias = b2[l];
#pragma unroll
            for (int r = 0; r < 4; ++r)
                out[(rowbase + myrg * 16 + 4 * q + r) * Pn + l] = sig_(yfc[r] + bias);
        }
    }
}

extern "C" void kernel_launch(void* const* d_in, const int* in_sizes, int n_in,
                              void* d_out, int out_size, void* d_ws, size_t ws_size,
                              hipStream_t stream) {
    const float* x    = (const float*)d_in[0];
    const float* W1   = (const float*)d_in[1];
    const float* b1   = (const float*)d_in[2];
    const float* Wih1 = (const float*)d_in[3];
    const float* Whh1 = (const float*)d_in[4];
    const float* bih1 = (const float*)d_in[5];
    const float* bhh1 = (const float*)d_in[6];
    const float* Wih2 = (const float*)d_in[7];
    const float* Whh2 = (const float*)d_in[8];
    const float* bih2 = (const float*)d_in[9];
    const float* bhh2 = (const float*)d_in[10];
    const float* W2   = (const float*)d_in[11];
    const float* b2   = (const float*)d_in[12];
    float* out = (float*)d_out;
    float* ws  = (float*)d_ws;

    prep_kernel<<<(512 + 3 * NFRAG * 64 + 28 * 64) / 256, 256, 0, stream>>>(
        W1, b1, Wih1, bih1, bhh1, Whh1, Wih2, Whh2, W2, ws);
    lstm_fused<<<Bn / 64, 1024, 0, stream>>>(x, ws, bih2, bhh2, b2, out);
}

// Round 9
// 223.195 us; speedup vs baseline: 1.7840x; 1.7840x over previous
//
#include <hip/hip_runtime.h>
#include <math.h>

// Problem constants
#define Tn 30
#define Bn 16384
#define Hn 100
#define Pn 7

// Tiling: gates padded 100->128 units => N=512 (32 n-tiles); K padded 100->128 (4 kt of 32).
// 256 blocks x 512 threads (8 waves) -- 512-thr blocks compile sanely (R6: VGPR 108, no
// spill; 1024-thr blocks force a 64-arch-VGPR split and spill 400+ GB, R7/R8).
// Wave ag (=wave id) owns unit-block ag (16 units, all 4 gates) for ALL 4 row-groups.
// B-frags (16/wave = 64 VGPR) in registers. gin2 in 16 packed-bf16 VGPRs.
// h double-buffered in LDS, frag-major [rg][kt][cell][8] with XOR swizzle
// cell = s*16 + (m^s): reads canonical conflict-free ds_read_b128, b16 writes 2-way
// same-dword (free, m136). 1 barrier/step.
#define NFRAG 128                      // B-frags per matrix (32 nt x 4 kt)
#define FRAG_BYTES (NFRAG * 64 * 16)   // 131072 per matrix
#define WS_FRAG_OFF 4096
#define WS_W2_OFF (WS_FRAG_OFF + 3 * FRAG_BYTES)   // 28 W2 frags (7 ps x 4 kt)
#define HBF_USH 8192                   // one h buffer: 4 rg x 4 kt x 64 cells x 8 ush (16 KB)

typedef __attribute__((ext_vector_type(8))) short short8;   // 8 bf16 (4 VGPRs)
typedef __attribute__((ext_vector_type(4))) float floatx4;  // MFMA C/D

__device__ __forceinline__ float rcp_(float v) { return __builtin_amdgcn_rcpf(v); }
__device__ __forceinline__ float sig_(float v) { return rcp_(1.0f + __expf(-v)); }
__device__ __forceinline__ float tanh_(float v) { return 1.0f - 2.0f * rcp_(__expf(2.0f * v) + 1.0f); }
__device__ __forceinline__ unsigned f2bf(float v) {
    unsigned u = __float_as_uint(v);
    return (u + 0x7FFFu + ((u >> 16) & 1u)) >> 16;   // RNE
}

// A-frag read, XOR-swizzled frag-major layout: cell(m,s) = s*16 + (m^s).
// Lane (l,q) of the reading wave needs A[m=l][k=kt*32+q*8+j] -> cell q*16 + (l^q).
__device__ __forceinline__ short8 ld_af(const unsigned short* buf, int rg, int kt, int l, int q) {
    return *(const short8*)(buf + ((rg * 4 + kt) * 64 + q * 16 + (l ^ q)) * 8);
}

// Merged prep: gid<512 -> u1/wc1 rank-1 FC1 fold; else pack Whh1/Wih2/Whh2 + W2 B-frags.
// B[k][n]: n = lane&15, k = (lane>>4)*8 + jj  (16x16x32 bf16 B mapping, HW-verified R4-R8).
__global__ void prep_kernel(const float* __restrict__ W1, const float* __restrict__ b1,
                            const float* __restrict__ Wih1, const float* __restrict__ bih1,
                            const float* __restrict__ bhh1, const float* __restrict__ Whh1,
                            const float* __restrict__ Wih2, const float* __restrict__ Whh2,
                            const float* __restrict__ W2, float* __restrict__ ws) {
    int gid = blockIdx.x * 256 + threadIdx.x;   // 512 + 3*8192 + 1792 = 26880 total
    if (gid < 512) {
        int j = gid;
        if (j < 400) {
            float u = 0.f, w = 0.f;
            for (int k = 0; k < Hn; ++k) {
                float a = Wih1[j * Hn + k];
                u += a * W1[k];
                w += a * b1[k];
            }
            ws[j] = u;
            ws[400 + j] = w + bih1[j] + bhh1[j];
        }
        return;
    }
    int g = gid - 512;
    int lane = g & 63;
    int l = lane & 15, q = lane >> 4;
    unsigned short hh[8];
    uint4 u;
    if (g < 3 * NFRAG * 64) {
        int mat = g / (NFRAG * 64);
        int f = (g % (NFRAG * 64)) >> 6;
        int nt = f >> 2, kt = f & 3;
        int G = nt >> 3, ag = nt & 7;
        int j = ag * 16 + l;
        const float* W = (mat == 0) ? Whh1 : (mat == 1) ? Wih2 : Whh2;
        const float* wrow = W + (G * Hn + (j < Hn ? j : 0)) * Hn;
        int kbase = kt * 32 + q * 8;
#pragma unroll
        for (int jj = 0; jj < 8; ++jj) {
            int k = kbase + jj;
            hh[jj] = (j < Hn && k < Hn) ? (unsigned short)f2bf(wrow[k]) : (unsigned short)0;
        }
        u.x = (unsigned)hh[0] | ((unsigned)hh[1] << 16);
        u.y = (unsigned)hh[2] | ((unsigned)hh[3] << 16);
        u.z = (unsigned)hh[4] | ((unsigned)hh[5] << 16);
        u.w = (unsigned)hh[6] | ((unsigned)hh[7] << 16);
        ((uint4*)((char*)ws + WS_FRAG_OFF + mat * FRAG_BYTES))[f * 64 + lane] = u;
    } else {
        int t = g - 3 * NFRAG * 64;             // 0..1791
        int f = t >> 6;                         // ps*4 + kt
        int ps = f >> 2, kt = f & 3;
        int kbase = kt * 32 + q * 8;
#pragma unroll
        for (int jj = 0; jj < 8; ++jj) {
            int k = kbase + jj;
            hh[jj] = (l < Pn && k < Hn) ? (unsigned short)f2bf(W2[l * (Pn * Hn) + ps * Hn + k])
                                        : (unsigned short)0;
        }
        u.x = (unsigned)hh[0] | ((unsigned)hh[1] << 16);
        u.y = (unsigned)hh[2] | ((unsigned)hh[3] << 16);
        u.z = (unsigned)hh[4] | ((unsigned)hh[5] << 16);
        u.w = (unsigned)hh[6] | ((unsigned)hh[7] << 16);
        ((uint4*)((char*)ws + WS_W2_OFF))[f * 64 + lane] = u;
    }
}

__global__ __launch_bounds__(512, 2) void lstm_fused(
    const float* __restrict__ x,     // (T,B)
    const float* __restrict__ ws,    // u1/wc1 + packed frags
    const float* __restrict__ bih2,
    const float* __restrict__ bhh2,
    const float* __restrict__ b2,    // (7,)
    float* __restrict__ out)         // (B,7)
{
    __shared__ unsigned short sm[2 * HBF_USH];  // 32 KB: h double buffer, frag-major swizzled
    unsigned short* hb0 = sm;
    unsigned short* hb1 = sm + HBF_USH;

    const int tid = threadIdx.x;
    const int ag = tid >> 6, lane = tid & 63;   // wave id == unit-block id
    const int l = lane & 15, q = lane >> 4;
    const int jcol = ag * 16 + l;               // unit column (0..127; <100 real)
    const int rowbase = blockIdx.x * 64;

    // h-write constants for this lane's unit jcol (k-dim position jcol):
    // kt_w = jcol>>5, s_w = (jcol>>3)&3, j_w = jcol&7;
    // ush addr = rg*2048 + hwconst + ((4q+r)^s_w)*8
    const int s_w = ((ag & 1) << 1) | (l >> 3);
    const int hwconst = (((ag >> 1) * 64 + s_w * 16) << 3) + (l & 7);

    // zero both h buffers (covers K-pad; pad units compute h=0 exactly each step)
    for (int i = tid; i < HBF_USH; i += 512) ((unsigned*)sm)[i] = 0;

    // this wave's 16 Whh1 B-frags -> registers (64 VGPR, held for all 30 steps)
    short8 bf[4][4];   // [G][kt]
    const short8* fr0 = (const short8*)((const char*)ws + WS_FRAG_OFF);
#pragma unroll
    for (int G = 0; G < 4; ++G)
#pragma unroll
        for (int kt = 0; kt < 4; ++kt)
            bf[G][kt] = fr0[((((G << 3) | ag) << 2) + kt) * 64 + lane];

    float u1v[4], wc1v[4];
#pragma unroll
    for (int G = 0; G < 4; ++G) {
        u1v[G] = (jcol < Hn) ? ws[G * Hn + jcol] : 0.f;
        wc1v[G] = (jcol < Hn) ? ws[400 + G * Hn + jcol] : 0.f;
    }
    floatx4 cst[4];   // cell state per rg, rows 4q+r, unit jcol
#pragma unroll
    for (int rg = 0; rg < 4; ++rg) cst[rg] = (floatx4){0.f, 0.f, 0.f, 0.f};

    __syncthreads();   // h buffers zeroed

    // ---- Phase 1: LSTM1, 30 steps, 1 barrier/step ----
    for (int t = 0; t < Tn; ++t) {
        const unsigned short* hc = (t & 1) ? hb1 : hb0;
        unsigned short* hn = (t & 1) ? hb0 : hb1;
#pragma unroll
        for (int rg = 0; rg < 4; ++rg) {
            float4 xv = *(const float4*)(x + t * Bn + rowbase + rg * 16 + 4 * q);
            floatx4 acc[4];
#pragma unroll
            for (int G = 0; G < 4; ++G)
#pragma unroll
                for (int r = 0; r < 4; ++r)
                    acc[G][r] = fmaf(xv[r], u1v[G], wc1v[G]);
#pragma unroll
            for (int kt = 0; kt < 4; ++kt) {
                short8 a = ld_af(hc, rg, kt, l, q);
#pragma unroll
                for (int G = 0; G < 4; ++G)
                    acc[G] = __builtin_amdgcn_mfma_f32_16x16x32_bf16(a, bf[G][kt], acc[G], 0, 0, 0);
            }
#pragma unroll
            for (int r = 0; r < 4; ++r) {
                float iv = sig_(acc[0][r]);
                float fv = sig_(acc[1][r]);
                float gv = tanh_(acc[2][r]);
                float ov = sig_(acc[3][r]);
                float cc = fv * cst[rg][r] + iv * gv;
                cst[rg][r] = cc;
                hn[rg * 2048 + hwconst + (((4 * q + r) ^ s_w) << 3)] =
                    (unsigned short)f2bf(ov * tanh_(cc));
            }
        }
        __syncthreads();
    }
    // hb0 holds `last` (h after t=29).

    // ---- Wih2 frags; gin2 = bias2 + last·Wih2^T kept in 32 packed-bf16 VGPRs ----
    {
        const short8* fr = (const short8*)((const char*)ws + WS_FRAG_OFF + FRAG_BYTES);
#pragma unroll
        for (int G = 0; G < 4; ++G)
#pragma unroll
            for (int kt = 0; kt < 4; ++kt)
                bf[G][kt] = fr[((((G << 3) | ag) << 2) + kt) * 64 + lane];
    }
    uint2 g2r[4][4];   // [rg][G] packed bf16 gin2 (wave-private cells)
    {
        float bv[4];
#pragma unroll
        for (int G = 0; G < 4; ++G)
            bv[G] = (jcol < Hn) ? (bih2[G * Hn + jcol] + bhh2[G * Hn + jcol]) : 0.f;
#pragma unroll
        for (int rg = 0; rg < 4; ++rg) {
            floatx4 acc[4];
#pragma unroll
            for (int G = 0; G < 4; ++G)
                acc[G] = (floatx4){bv[G], bv[G], bv[G], bv[G]};
#pragma unroll
            for (int kt = 0; kt < 4; ++kt) {
                short8 a = ld_af(hb0, rg, kt, l, q);
#pragma unroll
                for (int G = 0; G < 4; ++G)
                    acc[G] = __builtin_amdgcn_mfma_f32_16x16x32_bf16(a, bf[G][kt], acc[G], 0, 0, 0);
            }
#pragma unroll
            for (int G = 0; G < 4; ++G) {
                g2r[rg][G].x = f2bf(acc[G][0]) | (f2bf(acc[G][1]) << 16);
                g2r[rg][G].y = f2bf(acc[G][2]) | (f2bf(acc[G][3]) << 16);
            }
        }
    }
    // ---- Whh2 frags ----
    {
        const short8* fr = (const short8*)((const char*)ws + WS_FRAG_OFF + 2 * FRAG_BYTES);
#pragma unroll
        for (int G = 0; G < 4; ++G)
#pragma unroll
            for (int kt = 0; kt < 4; ++kt)
                bf[G][kt] = fr[((((G << 3) | ag) << 2) + kt) * 64 + lane];
    }

    // ---- Phase 2: LSTM2, 7 steps; FC2 via MFMA on waves ag<4 (rg = ag) ----
    const short8* w2fr = (const short8*)((const char*)ws + WS_W2_OFF);
    floatx4 yfc = (floatx4){0.f, 0.f, 0.f, 0.f};

    for (int ps = 0; ps < Pn; ++ps) {
        int t = Tn + ps;
        const unsigned short* hc = (t & 1) ? hb1 : hb0;
        unsigned short* hn = (t & 1) ? hb0 : hb1;
#pragma unroll
        for (int rg = 0; rg < 4; ++rg) {
            floatx4 acc[4];
#pragma unroll
            for (int G = 0; G < 4; ++G) {
                acc[G][0] = __uint_as_float(g2r[rg][G].x << 16);
                acc[G][1] = __uint_as_float(g2r[rg][G].x & 0xFFFF0000u);
                acc[G][2] = __uint_as_float(g2r[rg][G].y << 16);
                acc[G][3] = __uint_as_float(g2r[rg][G].y & 0xFFFF0000u);
            }
#pragma unroll
            for (int kt = 0; kt < 4; ++kt) {
                short8 a = ld_af(hc, rg, kt, l, q);
#pragma unroll
                for (int G = 0; G < 4; ++G)
                    acc[G] = __builtin_amdgcn_mfma_f32_16x16x32_bf16(a, bf[G][kt], acc[G], 0, 0, 0);
            }
#pragma unroll
            for (int r = 0; r < 4; ++r) {
                float iv = sig_(acc[0][r]);
                float fv = sig_(acc[1][r]);
                float gv = tanh_(acc[2][r]);
                float ov = sig_(acc[3][r]);
                float cc = fv * cst[rg][r] + iv * gv;
                cst[rg][r] = cc;
                hn[rg * 2048 + hwconst + (((4 * q + r) ^ s_w) << 3)] =
                    (unsigned short)f2bf(ov * tanh_(cc));
            }
        }
        // FC2: y[row][p] += h2^(ps) · W2-slice(ps-1); hc = h2 of previous step (stable)
        if (ag < 4 && ps >= 1) {
#pragma unroll
            for (int kt = 0; kt < 4; ++kt) {
                short8 a = ld_af(hc, ag, kt, l, q);
                short8 wf = w2fr[((ps - 1) * 4 + kt) * 64 + lane];
                yfc = __builtin_amdgcn_mfma_f32_16x16x32_bf16(a, wf, yfc, 0, 0, 0);
            }
        }
        __syncthreads();
    }

    // ---- final FC2 (h2^(7) in hb1: t=36 even -> hn=hb1, slice 6), bias+sigmoid+store ----
    if (ag < 4) {
#pragma unroll
        for (int kt = 0; kt < 4; ++kt) {
            short8 a = ld_af(hb1, ag, kt, l, q);
            short8 wf = w2fr[(6 * 4 + kt) * 64 + lane];
            yfc = __builtin_amdgcn_mfma_f32_16x16x32_bf16(a, wf, yfc, 0, 0, 0);
        }
        if (l < Pn) {
            float bias = b2[l];
#pragma unroll
            for (int r = 0; r < 4; ++r)
                out[(rowbase + ag * 16 + 4 * q + r) * Pn + l] = sig_(yfc[r] + bias);
        }
    }
}

extern "C" void kernel_launch(void* const* d_in, const int* in_sizes, int n_in,
                              void* d_out, int out_size, void* d_ws, size_t ws_size,
                              hipStream_t stream) {
    const float* x    = (const float*)d_in[0];
    const float* W1   = (const float*)d_in[1];
    const float* b1   = (const float*)d_in[2];
    const float* Wih1 = (const float*)d_in[3];
    const float* Whh1 = (const float*)d_in[4];
    const float* bih1 = (const float*)d_in[5];
    const float* bhh1 = (const float*)d_in[6];
    const float* Wih2 = (const float*)d_in[7];
    const float* Whh2 = (const float*)d_in[8];
    const float* bih2 = (const float*)d_in[9];
    const float* bhh2 = (const float*)d_in[10];
    const float* W2   = (const float*)d_in[11];
    const float* b2   = (const float*)d_in[12];
    float* out = (float*)d_out;
    float* ws  = (float*)d_ws;

    prep_kernel<<<(512 + 3 * NFRAG * 64 + 28 * 64) / 256, 256, 0, stream>>>(
        W1, b1, Wih1, bih1, bhh1, Whh1, Wih2, Whh2, W2, ws);
    lstm_fused<<<Bn / 64, 512, 0, stream>>>(x, ws, bih2, bhh2, b2, out);
}